// Round 1
// baseline (378.688 us; speedup 1.0000x reference)
//
#include <hip/hip_runtime.h>
#include <hip/hip_bf16.h>

// Problem constants
#define NB    2048   // batch
#define SS    200    // seq len
#define STP   208    // padded to 13*16
#define NTIL  13     // s-tiles of 16
#define DSEQ  256
#define DITEM 64
#define AA    128    // attn dim (H=1, HD=128)

typedef __bf16 bf16x8 __attribute__((ext_vector_type(8)));
typedef float  f32x4  __attribute__((ext_vector_type(4)));

__device__ __forceinline__ float prelu_f(float x, float a) { return x >= 0.f ? x : a * x; }

// ---------------- prep: convert W_k|W_v to bf16 [256][256], transpose ffn_W to [128][256]
__global__ void prep_kernel(const float* __restrict__ Wk, const float* __restrict__ Wv,
                            const float* __restrict__ ffnW,
                            __hip_bfloat16* __restrict__ Wb, float* __restrict__ ffnWt) {
    int idx = blockIdx.x * 256 + threadIdx.x;   // 384*256 = 98304 = 65536 + 32768
    if (idx < 256 * 256) {
        int a = idx >> 8, d = idx & 255;
        float v = (a < 128) ? Wk[a * 256 + d] : Wv[(a - 128) * 256 + d];
        Wb[idx] = __float2bfloat16(v);
    } else {
        int j = idx - 65536;                    // [0, 32768)
        int a = j >> 8, o = j & 255;
        ffnWt[a * 256 + o] = ffnW[o * 128 + a];
    }
}

// ---------------- main fused kernel: one block per batch row
__global__ __launch_bounds__(256, 2) void pool_main(
    const float* __restrict__ X,      // [2048,200,256]
    const int*   __restrict__ maskp,  // [2048,200] 1 = pad
    const float* __restrict__ temb,   // [2048,64]
    const float* __restrict__ Wq,     // [128,64]
    const float* __restrict__ Wker,   // [128,128]
    const float* __restrict__ ffnb,   // [256]
    const float* __restrict__ prelu_a,
    const __hip_bfloat16* __restrict__ Wb,   // ws [256][256] bf16 (rows 0..127 = K, 128..255 = V)
    const float* __restrict__ ffnWt,  // ws [128][256]
    float* __restrict__ out)          // [2048*256] ffn, then [2048*200] attn
{
    __shared__ float t_lds[DITEM];
    __shared__ float Q_lds[AA];
    __shared__ float u_lds[AA];
    __shared__ int   mask_lds[STP];
    __shared__ float sp[2][4][16];
    __shared__ float score_buf[STP];
    __shared__ float out_vec[AA];

    const int b    = blockIdx.x;
    const int tid  = threadIdx.x;
    const int w    = tid >> 6;        // wave 0..3
    const int lane = tid & 63;
    const int col  = lane & 15;
    const int rg   = lane >> 4;       // row group 0..3
    const float pa = *prelu_a;
    const float inv_scale = 0.08838834764831845f;  // 1/sqrt(128)

    // ---- stage small per-b inputs
    if (tid < DITEM) t_lds[tid] = temb[b * DITEM + tid];
    if (tid < STP)   mask_lds[tid] = (tid < SS) ? maskp[b * SS + tid] : 1;
    __syncthreads();

    // ---- Q = prelu(W_q @ t)
    if (tid < AA) {
        const f32x4* wr = reinterpret_cast<const f32x4*>(Wq + tid * DITEM);
        float acc = 0.f;
        #pragma unroll
        for (int d4 = 0; d4 < DITEM / 4; d4++) {
            f32x4 v = wr[d4];
            acc += v[0] * t_lds[d4 * 4 + 0] + v[1] * t_lds[d4 * 4 + 1]
                 + v[2] * t_lds[d4 * 4 + 2] + v[3] * t_lds[d4 * 4 + 3];
        }
        Q_lds[tid] = prelu_f(acc, pa);
    }
    __syncthreads();

    // ---- u = W_kernel @ Q
    if (tid < AA) {
        const f32x4* wr = reinterpret_cast<const f32x4*>(Wker + tid * AA);
        float acc = 0.f;
        #pragma unroll
        for (int c4 = 0; c4 < AA / 4; c4++) {
            f32x4 v = wr[c4];
            acc += v[0] * Q_lds[c4 * 4 + 0] + v[1] * Q_lds[c4 * 4 + 1]
                 + v[2] * Q_lds[c4 * 4 + 2] + v[3] * Q_lds[c4 * 4 + 3];
        }
        u_lds[tid] = acc;
    }
    __syncthreads();

    // ---- hoist weight B-fragments into registers (reused for all 13 s-tiles)
    const int rK0 = 32 * w + col;         // K cols 32w..32w+15, +16
    bf16x8 wk0[8], wk1[8], wv0[8], wv1[8];
    #pragma unroll
    for (int k = 0; k < 8; k++) {
        int off = k * 32 + rg * 8;
        wk0[k] = *reinterpret_cast<const bf16x8*>(Wb + (rK0      ) * 256 + off);
        wk1[k] = *reinterpret_cast<const bf16x8*>(Wb + (rK0 +  16) * 256 + off);
        wv0[k] = *reinterpret_cast<const bf16x8*>(Wb + (rK0 + 128) * 256 + off);
        wv1[k] = *reinterpret_cast<const bf16x8*>(Wb + (rK0 + 144) * 256 + off);
    }
    const float u0 = u_lds[32 * w + col];
    const float u1 = u_lds[32 * w + 16 + col];

    float m = -INFINITY, l = 0.f, out0 = 0.f, out1 = 0.f;

    // ---- main s-tile loop
    for (int t = 0; t < NTIL; t++) {
        const int s0 = t * 16;
        int srow = s0 + col; if (srow > SS - 1) srow = SS - 1;   // clamp padded rows
        const float* xrow = X + ((size_t)b * SS + srow) * DSEQ + rg * 8;

        f32x4 aK0 = {0.f,0.f,0.f,0.f}, aK1 = {0.f,0.f,0.f,0.f};
        f32x4 aV0 = {0.f,0.f,0.f,0.f}, aV1 = {0.f,0.f,0.f,0.f};

        #pragma unroll
        for (int k = 0; k < 8; k++) {
            f32x4 lo = *reinterpret_cast<const f32x4*>(xrow + k * 32);
            f32x4 hi = *reinterpret_cast<const f32x4*>(xrow + k * 32 + 4);
            bf16x8 af;
            af[0] = (__bf16)lo[0]; af[1] = (__bf16)lo[1]; af[2] = (__bf16)lo[2]; af[3] = (__bf16)lo[3];
            af[4] = (__bf16)hi[0]; af[5] = (__bf16)hi[1]; af[6] = (__bf16)hi[2]; af[7] = (__bf16)hi[3];
            aK0 = __builtin_amdgcn_mfma_f32_16x16x32_bf16(af, wk0[k], aK0, 0, 0, 0);
            aK1 = __builtin_amdgcn_mfma_f32_16x16x32_bf16(af, wk1[k], aK1, 0, 0, 0);
            aV0 = __builtin_amdgcn_mfma_f32_16x16x32_bf16(af, wv0[k], aV0, 0, 0, 0);
            aV1 = __builtin_amdgcn_mfma_f32_16x16x32_bf16(af, wv1[k], aV1, 0, 0, 0);
        }

        // score partials over this wave's 32 K-cols
        float pr[4];
        #pragma unroll
        for (int i = 0; i < 4; i++)
            pr[i] = prelu_f(aK0[i], pa) * u0 + prelu_f(aK1[i], pa) * u1;
        #pragma unroll
        for (int msk = 1; msk < 16; msk <<= 1) {
            #pragma unroll
            for (int i = 0; i < 4; i++) pr[i] += __shfl_xor(pr[i], msk, 64);
        }
        const int par = t & 1;
        if (col == 0) {
            #pragma unroll
            for (int i = 0; i < 4; i++) sp[par][w][rg * 4 + i] = pr[i];
        }
        __syncthreads();

        // full 16 scores (redundant per thread, all identical)
        float scarr[16];
        float tmax = -INFINITY;
        #pragma unroll
        for (int s = 0; s < 16; s++) {
            float sc = (sp[par][0][s] + sp[par][1][s] + sp[par][2][s] + sp[par][3][s]) * inv_scale;
            sc = mask_lds[s0 + s] ? -1e9f : sc;
            scarr[s] = sc;
            tmax = fmaxf(tmax, sc);
            if (tid == s) score_buf[s0 + s] = sc;   // wave-0 lanes persist raw scores
        }
        const float nm = fmaxf(m, tmax);
        const float f  = __expf(m - nm);
        float sum = 0.f, wx[4];
        #pragma unroll
        for (int s = 0; s < 16; s++) {
            float e = __expf(scarr[s] - nm);
            sum += e;
            if ((s >> 2) == rg) wx[s & 3] = e;
        }
        l = l * f + sum;
        m = nm;
        out0 *= f; out1 *= f;
        #pragma unroll
        for (int i = 0; i < 4; i++) {
            out0 += wx[i] * prelu_f(aV0[i], pa);
            out1 += wx[i] * prelu_f(aV1[i], pa);
        }
    }

    // ---- reduce V accumulation across row groups, normalize
    out0 += __shfl_xor(out0, 16, 64); out0 += __shfl_xor(out0, 32, 64);
    out1 += __shfl_xor(out1, 16, 64); out1 += __shfl_xor(out1, 32, 64);
    const float invl = 1.0f / l;
    if (lane < 16) {
        out_vec[32 * w + lane]      = out0 * invl;
        out_vec[32 * w + 16 + lane] = out1 * invl;
    }
    __syncthreads();

    // ---- attn output
    if (tid < SS) {
        out[(size_t)NB * DSEQ + (size_t)b * SS + tid] = __expf(score_buf[tid] - m) * invl;
    }

    // ---- FFN: ffn_out[o] = prelu(sum_a out_vec[a] * ffn_W[o,a] + b[o])
    float acc = ffnb[tid];
    #pragma unroll 8
    for (int a = 0; a < AA; a++) acc += out_vec[a] * ffnWt[a * 256 + tid];
    out[(size_t)b * DSEQ + tid] = prelu_f(acc, pa);
}

extern "C" void kernel_launch(void* const* d_in, const int* in_sizes, int n_in,
                              void* d_out, int out_size, void* d_ws, size_t ws_size,
                              hipStream_t stream) {
    const float* X    = (const float*)d_in[0];
    const int*   mask = (const int*)  d_in[1];
    const float* temb = (const float*)d_in[2];
    const float* Wq   = (const float*)d_in[3];
    const float* Wk   = (const float*)d_in[4];
    const float* Wv   = (const float*)d_in[5];
    const float* Wker = (const float*)d_in[6];
    const float* ffnW = (const float*)d_in[7];
    const float* ffnb = (const float*)d_in[8];
    const float* pa   = (const float*)d_in[9];
    float* out = (float*)d_out;

    __hip_bfloat16* Wb = (__hip_bfloat16*)d_ws;
    float* ffnWt = (float*)((char*)d_ws + 256 * 256 * sizeof(__hip_bfloat16));

    prep_kernel<<<384, 256, 0, stream>>>(Wk, Wv, ffnW, Wb, ffnWt);
    pool_main<<<NB, 256, 0, stream>>>(X, mask, temb, Wq, Wker, ffnb, pa, Wb, ffnWt, out);
}

// Round 2
// 221.506 us; speedup vs baseline: 1.7096x; 1.7096x over previous
//
#include <hip/hip_runtime.h>
#include <hip/hip_bf16.h>

// Problem constants
#define NB    2048   // batch
#define SS    200    // seq len
#define STP   208    // padded to 13*16
#define NTIL  13     // s-tiles of 16
#define DSEQ  256
#define DITEM 64
#define AA    128    // attn dim (H=1, HD=128)

typedef __bf16 bf16x8 __attribute__((ext_vector_type(8)));
typedef float  f32x4  __attribute__((ext_vector_type(4)));

typedef const __attribute__((address_space(1))) void gvoid_t;
typedef __attribute__((address_space(3))) void lvoid_t;

__device__ __forceinline__ float prelu_f(float x, float a) { return x >= 0.f ? x : a * x; }

// ---------------- prep: convert W_k|W_v to bf16 [256][256], transpose ffn_W to [128][256]
__global__ void prep_kernel(const float* __restrict__ Wk, const float* __restrict__ Wv,
                            const float* __restrict__ ffnW,
                            __hip_bfloat16* __restrict__ Wb, float* __restrict__ ffnWt) {
    int idx = blockIdx.x * 256 + threadIdx.x;   // 384*256 = 98304 = 65536 + 32768
    if (idx < 256 * 256) {
        int a = idx >> 8, d = idx & 255;
        float v = (a < 128) ? Wk[a * 256 + d] : Wv[(a - 128) * 256 + d];
        Wb[idx] = __float2bfloat16(v);
    } else {
        int j = idx - 65536;                    // [0, 32768)
        int a = j >> 8, o = j & 255;
        ffnWt[a * 256 + o] = ffnW[o * 128 + a];
    }
}

// Stage one 16x256-f32 X tile into LDS (wave w loads rows 4w..4w+3).
// LDS dest is linear (global_load_lds writes base + lane*16); the global
// source byte offset is pre-XOR-swizzled so that LDS[r][c ^ ((r&7)<<4)] = X[r][c].
__device__ __forceinline__ void issue_tile(const float* __restrict__ X, int b, int t,
                                           int w, int lane, float* ldsbuf) {
    #pragma unroll
    for (int j = 0; j < 4; j++) {
        const int row = w * 4 + j;
        int gr = t * 16 + row; if (gr > SS - 1) gr = SS - 1;     // clamp padded rows
        const char* gsrc = (const char*)(X + ((size_t)b * SS + gr) * DSEQ)
                         + ((lane * 16) ^ ((row & 7) << 4));
        char* ldst = (char*)ldsbuf + row * 1024;                  // wave-uniform base
        __builtin_amdgcn_global_load_lds((gvoid_t*)gsrc, (lvoid_t*)ldst, 16, 0, 0);
    }
}

// ---------------- main fused kernel: one block per batch row
__global__ __launch_bounds__(256, 2) void pool_main(
    const float* __restrict__ X,      // [2048,200,256]
    const int*   __restrict__ maskp,  // [2048,200] 1 = pad
    const float* __restrict__ temb,   // [2048,64]
    const float* __restrict__ Wq,     // [128,64]
    const float* __restrict__ Wker,   // [128,128]
    const float* __restrict__ ffnb,   // [256]
    const float* __restrict__ prelu_a,
    const __hip_bfloat16* __restrict__ Wb,   // ws [256][256] bf16 (rows 0..127 = K, 128..255 = V)
    const float* __restrict__ ffnWt,  // ws [128][256]
    float* __restrict__ out)          // [2048*256] ffn, then [2048*200] attn
{
    __shared__ float Xs[3][16][256];  // 48 KB, triple-buffered X tiles (swizzled layout)
    __shared__ float t_lds[DITEM];
    __shared__ float Q_lds[AA];
    __shared__ float u_lds[AA];
    __shared__ int   mask_lds[STP];
    __shared__ float sp[2][4][16];
    __shared__ float score_buf[STP];
    __shared__ float out_vec[AA];

    const int b    = blockIdx.x;
    const int tid  = threadIdx.x;
    const int w    = tid >> 6;        // wave 0..3
    const int lane = tid & 63;
    const int col  = lane & 15;       // s-row within tile (A-frag row)
    const int rg   = lane >> 4;       // k-group 0..3
    float pa = *prelu_a;
    const float inv_scale = 0.08838834764831845f;  // 1/sqrt(128)

    // ---- stage small per-b inputs
    if (tid < DITEM) t_lds[tid] = temb[b * DITEM + tid];
    if (tid < STP)   mask_lds[tid] = (tid < SS) ? maskp[b * SS + tid] : 1;
    __syncthreads();

    // ---- Q = prelu(W_q @ t)
    if (tid < AA) {
        const f32x4* wr = reinterpret_cast<const f32x4*>(Wq + tid * DITEM);
        float acc = 0.f;
        #pragma unroll
        for (int d4 = 0; d4 < DITEM / 4; d4++) {
            f32x4 v = wr[d4];
            acc += v[0] * t_lds[d4 * 4 + 0] + v[1] * t_lds[d4 * 4 + 1]
                 + v[2] * t_lds[d4 * 4 + 2] + v[3] * t_lds[d4 * 4 + 3];
        }
        Q_lds[tid] = prelu_f(acc, pa);
    }
    __syncthreads();

    // ---- u = W_kernel @ Q
    if (tid < AA) {
        const f32x4* wr = reinterpret_cast<const f32x4*>(Wker + tid * AA);
        float acc = 0.f;
        #pragma unroll
        for (int c4 = 0; c4 < AA / 4; c4++) {
            f32x4 v = wr[c4];
            acc += v[0] * Q_lds[c4 * 4 + 0] + v[1] * Q_lds[c4 * 4 + 1]
                 + v[2] * Q_lds[c4 * 4 + 2] + v[3] * Q_lds[c4 * 4 + 3];
        }
        u_lds[tid] = acc;
    }
    __syncthreads();

    // ---- hoist weight B-fragments into registers (reused for all 13 s-tiles)
    const int rK0 = 32 * w + col;         // K cols 32w..32w+15, +16
    bf16x8 wk0[8], wk1[8], wv0[8], wv1[8];
    #pragma unroll
    for (int k = 0; k < 8; k++) {
        int off = k * 32 + rg * 8;
        wk0[k] = *reinterpret_cast<const bf16x8*>(Wb + (rK0      ) * 256 + off);
        wk1[k] = *reinterpret_cast<const bf16x8*>(Wb + (rK0 +  16) * 256 + off);
        wv0[k] = *reinterpret_cast<const bf16x8*>(Wb + (rK0 + 128) * 256 + off);
        wv1[k] = *reinterpret_cast<const bf16x8*>(Wb + (rK0 + 144) * 256 + off);
    }
    float u0 = u_lds[32 * w + col];
    float u1 = u_lds[32 * w + 16 + col];

    // Force-materialize everything consumed inside the pipelined loop so no
    // compiler-scheduled VMEM pollutes the manual vmcnt counting below.
    #pragma unroll
    for (int k = 0; k < 8; k++) {
        asm volatile("" : "+v"(wk0[k]), "+v"(wk1[k]), "+v"(wv0[k]), "+v"(wv1[k]));
    }
    asm volatile("" : "+v"(pa), "+v"(u0), "+v"(u1));
    asm volatile("s_waitcnt vmcnt(0)" ::: "memory");

    // ---- software-pipelined main loop: depth-2 prefetch, 1 barrier/iter
    issue_tile(X, b, 0, w, lane, &Xs[0][0][0]);
    issue_tile(X, b, 1, w, lane, &Xs[1][0][0]);

    float m = -INFINITY, l = 0.f, out0 = 0.f, out1 = 0.f;
    f32x4 aVp0 = {0.f,0.f,0.f,0.f}, aVp1 = {0.f,0.f,0.f,0.f};
    const int swz = (col & 7) << 2;    // read-side swizzle, float units

    for (int t = 0; t < NTIL; t++) {
        // Wait own tile-t loads (oldest 4 of 8 outstanding), publish via barrier.
        if (t < NTIL - 1) asm volatile("s_waitcnt vmcnt(4) lgkmcnt(0)" ::: "memory");
        else              asm volatile("s_waitcnt vmcnt(0) lgkmcnt(0)" ::: "memory");
        __builtin_amdgcn_s_barrier();
        __builtin_amdgcn_sched_barrier(0);   // pin LDS reads behind the barrier

        // prefetch tile t+2 into the buffer freed at the barrier above
        if (t + 2 < NTIL) issue_tile(X, b, t + 2, w, lane, &Xs[(t + 2) % 3][0][0]);

        // ---- deferred softmax of tile t-1 (sp[(t-1)&1] now visible)
        if (t > 0) {
            const int q   = (t - 1) & 1;
            const int s0p = (t - 1) * 16;
            float scarr[16];
            float tmax = -INFINITY;
            #pragma unroll
            for (int s = 0; s < 16; s++) {
                float sc = (sp[q][0][s] + sp[q][1][s] + sp[q][2][s] + sp[q][3][s]) * inv_scale;
                sc = mask_lds[s0p + s] ? -1e9f : sc;
                scarr[s] = sc;
                tmax = fmaxf(tmax, sc);
                if (tid == s) score_buf[s0p + s] = sc;
            }
            const float nm = fmaxf(m, tmax);
            const float f  = __expf(m - nm);
            float sum = 0.f, wx[4];
            #pragma unroll
            for (int s = 0; s < 16; s++) {
                float e = __expf(scarr[s] - nm);
                sum += e;
                if ((s >> 2) == rg) wx[s & 3] = e;
            }
            l = l * f + sum;
            m = nm;
            out0 *= f; out1 *= f;
            #pragma unroll
            for (int i = 0; i < 4; i++) {
                out0 += wx[i] * prelu_f(aVp0[i], pa);
                out1 += wx[i] * prelu_f(aVp1[i], pa);
            }
        }

        // ---- MFMA for tile t from LDS (swizzled reads, bank-floor pattern)
        const float* xt = &Xs[t % 3][0][0] + col * 256;
        f32x4 aK0 = {0.f,0.f,0.f,0.f}, aK1 = {0.f,0.f,0.f,0.f};
        f32x4 aV0 = {0.f,0.f,0.f,0.f}, aV1 = {0.f,0.f,0.f,0.f};
        #pragma unroll
        for (int k = 0; k < 8; k++) {
            const int base = k * 32 + rg * 8;
            f32x4 lo = *reinterpret_cast<const f32x4*>(xt + ((base    ) ^ swz));
            f32x4 hi = *reinterpret_cast<const f32x4*>(xt + ((base + 4) ^ swz));
            bf16x8 af;
            af[0] = (__bf16)lo[0]; af[1] = (__bf16)lo[1]; af[2] = (__bf16)lo[2]; af[3] = (__bf16)lo[3];
            af[4] = (__bf16)hi[0]; af[5] = (__bf16)hi[1]; af[6] = (__bf16)hi[2]; af[7] = (__bf16)hi[3];
            aK0 = __builtin_amdgcn_mfma_f32_16x16x32_bf16(af, wk0[k], aK0, 0, 0, 0);
            aK1 = __builtin_amdgcn_mfma_f32_16x16x32_bf16(af, wk1[k], aK1, 0, 0, 0);
            aV0 = __builtin_amdgcn_mfma_f32_16x16x32_bf16(af, wv0[k], aV0, 0, 0, 0);
            aV1 = __builtin_amdgcn_mfma_f32_16x16x32_bf16(af, wv1[k], aV1, 0, 0, 0);
        }

        // score partials over this wave's 32 K-cols -> sp[t&1]
        float pr[4];
        #pragma unroll
        for (int i = 0; i < 4; i++)
            pr[i] = prelu_f(aK0[i], pa) * u0 + prelu_f(aK1[i], pa) * u1;
        #pragma unroll
        for (int msk = 1; msk < 16; msk <<= 1) {
            #pragma unroll
            for (int i = 0; i < 4; i++) pr[i] += __shfl_xor(pr[i], msk, 64);
        }
        if (col == 0) {
            #pragma unroll
            for (int i = 0; i < 4; i++) sp[t & 1][w][rg * 4 + i] = pr[i];
        }
        aVp0 = aV0; aVp1 = aV1;
    }

    // ---- epilogue: softmax of last tile
    asm volatile("s_waitcnt lgkmcnt(0)" ::: "memory");
    __builtin_amdgcn_s_barrier();
    __builtin_amdgcn_sched_barrier(0);
    {
        const int q   = (NTIL - 1) & 1;
        const int s0p = (NTIL - 1) * 16;
        float scarr[16];
        float tmax = -INFINITY;
        #pragma unroll
        for (int s = 0; s < 16; s++) {
            float sc = (sp[q][0][s] + sp[q][1][s] + sp[q][2][s] + sp[q][3][s]) * inv_scale;
            sc = mask_lds[s0p + s] ? -1e9f : sc;
            scarr[s] = sc;
            tmax = fmaxf(tmax, sc);
            if (tid == s) score_buf[s0p + s] = sc;
        }
        const float nm = fmaxf(m, tmax);
        const float f  = __expf(m - nm);
        float sum = 0.f, wx[4];
        #pragma unroll
        for (int s = 0; s < 16; s++) {
            float e = __expf(scarr[s] - nm);
            sum += e;
            if ((s >> 2) == rg) wx[s & 3] = e;
        }
        l = l * f + sum;
        m = nm;
        out0 *= f; out1 *= f;
        #pragma unroll
        for (int i = 0; i < 4; i++) {
            out0 += wx[i] * prelu_f(aVp0[i], pa);
            out1 += wx[i] * prelu_f(aVp1[i], pa);
        }
    }

    // ---- reduce V accumulation across row groups, normalize
    out0 += __shfl_xor(out0, 16, 64); out0 += __shfl_xor(out0, 32, 64);
    out1 += __shfl_xor(out1, 16, 64); out1 += __shfl_xor(out1, 32, 64);
    const float invl = 1.0f / l;
    if (lane < 16) {
        out_vec[32 * w + lane]      = out0 * invl;
        out_vec[32 * w + 16 + lane] = out1 * invl;
    }
    __syncthreads();

    // ---- attn output
    if (tid < SS) {
        out[(size_t)NB * DSEQ + (size_t)b * SS + tid] = __expf(score_buf[tid] - m) * invl;
    }

    // ---- FFN: ffn_out[o] = prelu(sum_a out_vec[a] * ffn_W[o,a] + b[o])
    float acc = ffnb[tid];
    #pragma unroll 8
    for (int a = 0; a < AA; a++) acc += out_vec[a] * ffnWt[a * 256 + tid];
    out[(size_t)b * DSEQ + tid] = prelu_f(acc, pa);
}

extern "C" void kernel_launch(void* const* d_in, const int* in_sizes, int n_in,
                              void* d_out, int out_size, void* d_ws, size_t ws_size,
                              hipStream_t stream) {
    const float* X    = (const float*)d_in[0];
    const int*   mask = (const int*)  d_in[1];
    const float* temb = (const float*)d_in[2];
    const float* Wq   = (const float*)d_in[3];
    const float* Wk   = (const float*)d_in[4];
    const float* Wv   = (const float*)d_in[5];
    const float* Wker = (const float*)d_in[6];
    const float* ffnW = (const float*)d_in[7];
    const float* ffnb = (const float*)d_in[8];
    const float* pa   = (const float*)d_in[9];
    float* out = (float*)d_out;

    __hip_bfloat16* Wb = (__hip_bfloat16*)d_ws;
    float* ffnWt = (float*)((char*)d_ws + 256 * 256 * sizeof(__hip_bfloat16));

    prep_kernel<<<384, 256, 0, stream>>>(Wk, Wv, ffnW, Wb, ffnWt);
    pool_main<<<NB, 256, 0, stream>>>(X, mask, temb, Wq, Wker, ffnb, pa, Wb, ffnWt, out);
}